// Round 3
// baseline (4054.265 us; speedup 1.0000x reference)
//
#include <hip/hip_runtime.h>

// LSTM: 4 layers, T=512, B=256, INPUT=100, H=128, gates=512 (i,f,g,o)
// Round 2: fp32 throughout.
//  - lstm_rec rewritten: 1024 thr, thread (q=tid>>3, p=tid&7) computes all 4
//    gates of unit q over k-slice [16p,16p+16). Weights w[4][16] = 64 VGPR,
//    guaranteed resident under launch_bounds(1024,4) (cap 128). Round-1 had
//    VGPR_Count=84 with 128 declared weights => compiler re-fetched weights
//    from L1/L2 every step (the real bottleneck).
//  - 3-level shfl_xor butterfly (1,2,4) -> all lanes get full i,f,g,o.
//  - LDS h: 16-unit groups padded to 20 words; p-group bases mod 32 =
//    {0,20,8,28,16,4,24,12} -> ds_read_b128 covers all 32 banks once.
// ws: io [512*256*128]f32 @0 (67MB) | xg [64*256*512]f32 @67MB (33.5MB)
//     | hstate,cstate @100.6MB  => ~101MB total (known-safe size).

#define TSTEPS 512
#define BATCH  256
#define HID    128
#define GATES  512
#define TC     64

__device__ __forceinline__ float sigmoid_f(float x) {
    return 1.0f / (1.0f + __expf(-x));
}
__device__ __forceinline__ float tanh_f(float x) {
    float e = __expf(2.0f * x);
    return 1.0f - 2.0f / (e + 1.0f);
}

// ---------------- input-projection GEMM ----------------
// XG[r, j] = A[row r, :]·W[j, :] + b_ih[j] + b_hh[j]
// rows r = q*256 + b (t = t0+q), cols j in [0,512). 64x64 tile, 256 thr, 4x4.
template<int K, bool L0>
__global__ __launch_bounds__(256, 4)
void gemm_xg(const float* __restrict__ A, const float* __restrict__ W,
             const float* __restrict__ bih, const float* __restrict__ bhh,
             float* __restrict__ XG, int t0)
{
    __shared__ float As[32][68];  // As[kk][row]
    __shared__ float Bs[32][68];  // Bs[kk][col]
    const int tid  = threadIdx.x;
    const int flat = blockIdx.y * 8 + blockIdx.x;   // [0,2048)
    const int rt   = flat & 255;   // row tile
    const int ct   = flat >> 8;    // col tile 0..7
    const int j0   = ct * 64;
    const int R0   = rt * 64;
    const int ty = tid >> 4, tx = tid & 15;

    float acc[4][4] = {};

    for (int kt = 0; kt < K; kt += 32) {
        #pragma unroll
        for (int i = 0; i < 8; ++i) {
            int f  = tid + 256 * i;
            int r  = f >> 5, kk = f & 31;
            int k  = kt + kk;
            int Rg = R0 + r;
            int q  = Rg >> 8, b = Rg & 255;
            float av = 0.f, wv = 0.f;
            if (K == 128 || k < K) {
                av = L0 ? A[(b * TSTEPS + (t0 + q)) * K + k]
                        : A[((t0 + q) * BATCH + b) * K + k];
                wv = W[(j0 + r) * K + k];
            }
            As[kk][r] = av;
            Bs[kk][r] = wv;
        }
        __syncthreads();
        #pragma unroll 8
        for (int kk = 0; kk < 32; ++kk) {
            float4 a4 = *(const float4*)&As[kk][ty * 4];
            float4 b4 = *(const float4*)&Bs[kk][tx * 4];
            float aa[4] = {a4.x, a4.y, a4.z, a4.w};
            float bb[4] = {b4.x, b4.y, b4.z, b4.w};
            #pragma unroll
            for (int ii = 0; ii < 4; ++ii)
                #pragma unroll
                for (int jj = 0; jj < 4; ++jj)
                    acc[ii][jj] = fmaf(aa[ii], bb[jj], acc[ii][jj]);
        }
        __syncthreads();
    }

    float4 bi = *(const float4*)&bih[j0 + tx * 4];
    float4 bh = *(const float4*)&bhh[j0 + tx * 4];
    float bsum[4] = {bi.x + bh.x, bi.y + bh.y, bi.z + bh.z, bi.w + bh.w};
    #pragma unroll
    for (int ii = 0; ii < 4; ++ii) {
        int Rg = R0 + ty * 4 + ii;
        float4 st = {acc[ii][0] + bsum[0], acc[ii][1] + bsum[1],
                     acc[ii][2] + bsum[2], acc[ii][3] + bsum[3]};
        *(float4*)&XG[Rg * GATES + j0 + tx * 4] = st;
    }
}

// ---------------- recurrent scan ----------------
// One block (1024 thr) per batch row. Thread (q = tid>>3, p = tid&7) owns all
// 4 gates of hidden unit q over k-slice [16p, 16p+16). 64 weight VGPRs.
// 3-level butterfly -> every lane gets complete i,f,g,o.
__global__ __launch_bounds__(1024, 4)
void lstm_rec(const float* __restrict__ XG, const float* __restrict__ Whh,
              float* __restrict__ Hout,
              float* __restrict__ hstate, float* __restrict__ cstate,
              int t0, int first)
{
    const int b   = blockIdx.x;
    const int tid = threadIdx.x;
    const int q   = tid >> 3;   // hidden unit 0..127
    const int p   = tid & 7;    // k-slice 0..7
    // unit u stored at (u>>4)*20 + (u&15): 16-unit groups, stride 20 words.
    __shared__ float hbuf[2][160];

    // w[g][m] = Whh[g*128+q][16p+m]  -> 64 resident VGPRs
    float w[4][16];
    #pragma unroll
    for (int g = 0; g < 4; ++g) {
        const float* wp = Whh + (g * HID + q) * HID + p * 16;
        #pragma unroll
        for (int j = 0; j < 4; ++j) {
            float4 v = *(const float4*)(wp + 4 * j);
            w[g][4*j+0] = v.x; w[g][4*j+1] = v.y;
            w[g][4*j+2] = v.z; w[g][4*j+3] = v.w;
        }
    }

    float c;
    if (first) {
        c = 0.f;
        if (p == 0) hbuf[0][(q >> 4) * 20 + (q & 15)] = 0.f;
    } else {
        c = cstate[b * HID + q];
        if (p == 0) hbuf[0][(q >> 4) * 20 + (q & 15)] = hstate[b * HID + q];
    }
    __syncthreads();

    // lane p<4 streams gate p's xg for unit q
    const float* xgp = XG + b * GATES + (p & 3) * HID + q;
    float xg_val = (p < 4) ? xgp[0] : 0.f;
    float h = 0.f;
    int cur = 0;
    const int hbase = p * 20;   // this lane's 16-unit slice base
    for (int s = 0; s < TC; ++s) {
        float xg_next = 0.f;
        if (p < 4 && s + 1 < TC) xg_next = xgp[(s + 1) * (BATCH * GATES)];

        float g0 = (p == 0) ? xg_val : 0.f;
        float g1 = (p == 1) ? xg_val : 0.f;
        float g2 = (p == 2) ? xg_val : 0.f;
        float g3 = (p == 3) ? xg_val : 0.f;
        #pragma unroll
        for (int j = 0; j < 4; ++j) {
            float4 hv = *(const float4*)&hbuf[cur][hbase + 4 * j];
            g0 = fmaf(w[0][4*j+0], hv.x, g0);
            g1 = fmaf(w[1][4*j+0], hv.x, g1);
            g2 = fmaf(w[2][4*j+0], hv.x, g2);
            g3 = fmaf(w[3][4*j+0], hv.x, g3);
            g0 = fmaf(w[0][4*j+1], hv.y, g0);
            g1 = fmaf(w[1][4*j+1], hv.y, g1);
            g2 = fmaf(w[2][4*j+1], hv.y, g2);
            g3 = fmaf(w[3][4*j+1], hv.y, g3);
            g0 = fmaf(w[0][4*j+2], hv.z, g0);
            g1 = fmaf(w[1][4*j+2], hv.z, g1);
            g2 = fmaf(w[2][4*j+2], hv.z, g2);
            g3 = fmaf(w[3][4*j+2], hv.z, g3);
            g0 = fmaf(w[0][4*j+3], hv.w, g0);
            g1 = fmaf(w[1][4*j+3], hv.w, g1);
            g2 = fmaf(w[2][4*j+3], hv.w, g2);
            g3 = fmaf(w[3][4*j+3], hv.w, g3);
        }
        // 3-level butterfly across the 8 p-lanes
        g0 += __shfl_xor(g0, 1); g0 += __shfl_xor(g0, 2); g0 += __shfl_xor(g0, 4);
        g1 += __shfl_xor(g1, 1); g1 += __shfl_xor(g1, 2); g1 += __shfl_xor(g1, 4);
        g2 += __shfl_xor(g2, 1); g2 += __shfl_xor(g2, 2); g2 += __shfl_xor(g2, 4);
        g3 += __shfl_xor(g3, 1); g3 += __shfl_xor(g3, 2); g3 += __shfl_xor(g3, 4);

        c = sigmoid_f(g1) * c + sigmoid_f(g0) * tanh_f(g2);
        h = sigmoid_f(g3) * tanh_f(c);

        if (p == 0) {
            hbuf[cur ^ 1][(q >> 4) * 20 + (q & 15)] = h;
            Hout[((t0 + s) * BATCH + b) * HID + q] = h;
        }
        __syncthreads();
        cur ^= 1;
        xg_val = xg_next;
    }
    if (p == 0) {
        hstate[b * HID + q] = h;
        cstate[b * HID + q] = c;
    }
}

// ---------------- final FC ----------------
__global__ __launch_bounds__(512)
void fc_kernel(const float* __restrict__ hstate, const float* __restrict__ fcw,
               const float* __restrict__ fcb, float* __restrict__ out)
{
    int idx = threadIdx.x;      // 512 = 256 rows x 2 outs
    int b = idx >> 1, o = idx & 1;
    float acc = fcb[o];
    #pragma unroll
    for (int k = 0; k < HID; ++k)
        acc = fmaf(hstate[b * HID + k], fcw[o * HID + k], acc);
    out[b * 2 + o] = acc;
}

extern "C" void kernel_launch(void* const* d_in, const int* in_sizes, int n_in,
                              void* d_out, int out_size, void* d_ws, size_t ws_size,
                              hipStream_t stream)
{
    const float* x = (const float*)d_in[0];
    const float* w_ih[4]; const float* w_hh[4];
    const float* b_ih[4]; const float* b_hh[4];
    for (int l = 0; l < 4; ++l) {
        w_ih[l] = (const float*)d_in[1 + 4 * l];
        w_hh[l] = (const float*)d_in[2 + 4 * l];
        b_ih[l] = (const float*)d_in[3 + 4 * l];
        b_hh[l] = (const float*)d_in[4 + 4 * l];
    }
    const float* fc_w = (const float*)d_in[17];
    const float* fc_b = (const float*)d_in[18];
    float* out = (float*)d_out;

    char* wsb = (char*)d_ws;
    float* io  = (float*)wsb;                                   // 67,108,864 B
    float* xg  = (float*)(wsb + 67108864);                      // 33,554,432 B
    float* hst = (float*)(wsb + 67108864 + 33554432);           // 131,072 B
    float* cst = hst + BATCH * HID;                             // 131,072 B

    dim3 ggrid(8, 256);  // x = col tile (fast), y = row tile
    for (int l = 0; l < 4; ++l) {
        for (int cchunk = 0; cchunk < TSTEPS / TC; ++cchunk) {
            int t0 = cchunk * TC;
            if (l == 0)
                gemm_xg<100, true><<<ggrid, 256, 0, stream>>>(x, w_ih[0], b_ih[0], b_hh[0], xg, t0);
            else
                gemm_xg<128, false><<<ggrid, 256, 0, stream>>>(io, w_ih[l], b_ih[l], b_hh[l], xg, t0);
            lstm_rec<<<256, 1024, 0, stream>>>(xg, w_hh[l], io, hst, cst, t0, cchunk == 0 ? 1 : 0);
        }
    }
    fc_kernel<<<1, 512, 0, stream>>>(hst, fc_w, fc_b, out);
}

// Round 4
// 3071.450 us; speedup vs baseline: 1.3200x; 1.3200x over previous
//
#include <hip/hip_runtime.h>

// LSTM: 4 layers, T=512, B=256, INPUT=100, H=128, gates=512 (i,f,g,o)
// Round 3: fp32 throughout.
//  - lstm_rec: round-1 quad structure (512 thr, thread (q,p) = all 4 gates of
//    unit q over k-slice [32p,32p+32), w[4][32] = 128 weight VGPRs), PLUS:
//      * __attribute__((amdgpu_waves_per_eu(2,2))): pins the scheduler's
//        occupancy target at 2 waves/SIMD (256-VGPR budget). Rounds 1/2 showed
//        VGPR_Count=84/48 < declared weights: the backend targets max
//        occupancy and re-loads weights from L2 every step (~4.2GB/dispatch).
//      * asm memory fence after weight loads: loads cannot sink into the loop.
//    Verification signal: VGPR_Count >= ~150.
//  - gemm_xg / fc unchanged.
// ws: io [512*256*128]f32 @0 (67MB) | xg [64*256*512]f32 @67MB (33.5MB)
//     | hstate,cstate @100.6MB  => ~101MB total (known-safe size).

#define TSTEPS 512
#define BATCH  256
#define HID    128
#define GATES  512
#define TC     64

__device__ __forceinline__ float sigmoid_f(float x) {
    return 1.0f / (1.0f + __expf(-x));
}
__device__ __forceinline__ float tanh_f(float x) {
    float e = __expf(2.0f * x);
    return 1.0f - 2.0f / (e + 1.0f);
}

// ---------------- input-projection GEMM ----------------
// XG[r, j] = A[row r, :]·W[j, :] + b_ih[j] + b_hh[j]
// rows r = q*256 + b (t = t0+q), cols j in [0,512). 64x64 tile, 256 thr, 4x4.
template<int K, bool L0>
__global__ __launch_bounds__(256, 4)
void gemm_xg(const float* __restrict__ A, const float* __restrict__ W,
             const float* __restrict__ bih, const float* __restrict__ bhh,
             float* __restrict__ XG, int t0)
{
    __shared__ float As[32][68];  // As[kk][row]
    __shared__ float Bs[32][68];  // Bs[kk][col]
    const int tid  = threadIdx.x;
    const int flat = blockIdx.y * 8 + blockIdx.x;   // [0,2048)
    const int rt   = flat & 255;   // row tile
    const int ct   = flat >> 8;    // col tile 0..7
    const int j0   = ct * 64;
    const int R0   = rt * 64;
    const int ty = tid >> 4, tx = tid & 15;

    float acc[4][4] = {};

    for (int kt = 0; kt < K; kt += 32) {
        #pragma unroll
        for (int i = 0; i < 8; ++i) {
            int f  = tid + 256 * i;
            int r  = f >> 5, kk = f & 31;
            int k  = kt + kk;
            int Rg = R0 + r;
            int q  = Rg >> 8, b = Rg & 255;
            float av = 0.f, wv = 0.f;
            if (K == 128 || k < K) {
                av = L0 ? A[(b * TSTEPS + (t0 + q)) * K + k]
                        : A[((t0 + q) * BATCH + b) * K + k];
                wv = W[(j0 + r) * K + k];
            }
            As[kk][r] = av;
            Bs[kk][r] = wv;
        }
        __syncthreads();
        #pragma unroll 8
        for (int kk = 0; kk < 32; ++kk) {
            float4 a4 = *(const float4*)&As[kk][ty * 4];
            float4 b4 = *(const float4*)&Bs[kk][tx * 4];
            float aa[4] = {a4.x, a4.y, a4.z, a4.w};
            float bb[4] = {b4.x, b4.y, b4.z, b4.w};
            #pragma unroll
            for (int ii = 0; ii < 4; ++ii)
                #pragma unroll
                for (int jj = 0; jj < 4; ++jj)
                    acc[ii][jj] = fmaf(aa[ii], bb[jj], acc[ii][jj]);
        }
        __syncthreads();
    }

    float4 bi = *(const float4*)&bih[j0 + tx * 4];
    float4 bh = *(const float4*)&bhh[j0 + tx * 4];
    float bsum[4] = {bi.x + bh.x, bi.y + bh.y, bi.z + bh.z, bi.w + bh.w};
    #pragma unroll
    for (int ii = 0; ii < 4; ++ii) {
        int Rg = R0 + ty * 4 + ii;
        float4 st = {acc[ii][0] + bsum[0], acc[ii][1] + bsum[1],
                     acc[ii][2] + bsum[2], acc[ii][3] + bsum[3]};
        *(float4*)&XG[Rg * GATES + j0 + tx * 4] = st;
    }
}

// ---------------- recurrent scan ----------------
// One block (512 thr) per batch row. Thread (q = tid>>2, p = tid&3) owns all
// 4 gates of hidden unit q over k-slice [32p,32p+32). 128 weight VGPRs,
// quad butterfly -> every lane gets complete i,f,g,o. One barrier/step.
__global__ __attribute__((amdgpu_waves_per_eu(2, 2))) __launch_bounds__(512)
void lstm_rec(const float* __restrict__ XG, const float* __restrict__ Whh,
              float* __restrict__ Hout,
              float* __restrict__ hstate, float* __restrict__ cstate,
              int t0, int first)
{
    const int b   = blockIdx.x;
    const int tid = threadIdx.x;
    const int q   = tid >> 2;   // hidden unit 0..127
    const int p   = tid & 3;    // k-slice 0..3
    __shared__ float hbuf[2][144];  // unit u at u + 4*(u>>5); slice p at 36p

    // w[g][m] = Whh[g*128+q][32p+m] -> 128 resident VGPRs
    float w[4][32];
    #pragma unroll
    for (int g = 0; g < 4; ++g) {
        const float* wp = Whh + (g * HID + q) * HID + p * 32;
        #pragma unroll
        for (int j = 0; j < 8; ++j) {
            float4 v = *(const float4*)(wp + 4 * j);
            w[g][4*j+0] = v.x; w[g][4*j+1] = v.y;
            w[g][4*j+2] = v.z; w[g][4*j+3] = v.w;
        }
    }
    // fence: weight loads cannot sink below this point (memory clobber)
    asm volatile("" ::: "memory");

    float c;
    if (first) {
        c = 0.f;
        if (p == 0) hbuf[0][(q) + 4 * (q >> 5)] = 0.f;
    } else {
        c = cstate[b * HID + q];
        if (p == 0) hbuf[0][(q) + 4 * (q >> 5)] = hstate[b * HID + q];
    }
    __syncthreads();

    // lane p streams gate p's xg for unit q
    const float* xgp = XG + b * GATES + p * HID + q;
    float xg_val = xgp[0];
    float h = 0.f;
    int cur = 0;
    const int hbase = 36 * p;   // slice base: banks {0,4,8,12}+, broadcast x16
    for (int s = 0; s < TC; ++s) {
        float xg_next = 0.f;
        if (s + 1 < TC) xg_next = xgp[(s + 1) * (BATCH * GATES)];

        float g0 = (p == 0) ? xg_val : 0.f;
        float g1 = (p == 1) ? xg_val : 0.f;
        float g2 = (p == 2) ? xg_val : 0.f;
        float g3 = (p == 3) ? xg_val : 0.f;
        #pragma unroll
        for (int j = 0; j < 8; ++j) {
            float4 hv = *(const float4*)&hbuf[cur][hbase + 4 * j];
            g0 = fmaf(w[0][4*j+0], hv.x, g0);
            g1 = fmaf(w[1][4*j+0], hv.x, g1);
            g2 = fmaf(w[2][4*j+0], hv.x, g2);
            g3 = fmaf(w[3][4*j+0], hv.x, g3);
            g0 = fmaf(w[0][4*j+1], hv.y, g0);
            g1 = fmaf(w[1][4*j+1], hv.y, g1);
            g2 = fmaf(w[2][4*j+1], hv.y, g2);
            g3 = fmaf(w[3][4*j+1], hv.y, g3);
            g0 = fmaf(w[0][4*j+2], hv.z, g0);
            g1 = fmaf(w[1][4*j+2], hv.z, g1);
            g2 = fmaf(w[2][4*j+2], hv.z, g2);
            g3 = fmaf(w[3][4*j+2], hv.z, g3);
            g0 = fmaf(w[0][4*j+3], hv.w, g0);
            g1 = fmaf(w[1][4*j+3], hv.w, g1);
            g2 = fmaf(w[2][4*j+3], hv.w, g2);
            g3 = fmaf(w[3][4*j+3], hv.w, g3);
        }
        // quad butterfly: all 4 p-lanes end with full i,f,g,o
        g0 += __shfl_xor(g0, 1); g0 += __shfl_xor(g0, 2);
        g1 += __shfl_xor(g1, 1); g1 += __shfl_xor(g1, 2);
        g2 += __shfl_xor(g2, 1); g2 += __shfl_xor(g2, 2);
        g3 += __shfl_xor(g3, 1); g3 += __shfl_xor(g3, 2);

        c = sigmoid_f(g1) * c + sigmoid_f(g0) * tanh_f(g2);
        h = sigmoid_f(g3) * tanh_f(c);

        if (p == 0) {
            hbuf[cur ^ 1][q + 4 * (q >> 5)] = h;
            Hout[((t0 + s) * BATCH + b) * HID + q] = h;
        }
        __syncthreads();
        cur ^= 1;
        xg_val = xg_next;
    }
    if (p == 0) {
        hstate[b * HID + q] = h;
        cstate[b * HID + q] = c;
    }
}

// ---------------- final FC ----------------
__global__ __launch_bounds__(512)
void fc_kernel(const float* __restrict__ hstate, const float* __restrict__ fcw,
               const float* __restrict__ fcb, float* __restrict__ out)
{
    int idx = threadIdx.x;      // 512 = 256 rows x 2 outs
    int b = idx >> 1, o = idx & 1;
    float acc = fcb[o];
    #pragma unroll
    for (int k = 0; k < HID; ++k)
        acc = fmaf(hstate[b * HID + k], fcw[o * HID + k], acc);
    out[b * 2 + o] = acc;
}

extern "C" void kernel_launch(void* const* d_in, const int* in_sizes, int n_in,
                              void* d_out, int out_size, void* d_ws, size_t ws_size,
                              hipStream_t stream)
{
    const float* x = (const float*)d_in[0];
    const float* w_ih[4]; const float* w_hh[4];
    const float* b_ih[4]; const float* b_hh[4];
    for (int l = 0; l < 4; ++l) {
        w_ih[l] = (const float*)d_in[1 + 4 * l];
        w_hh[l] = (const float*)d_in[2 + 4 * l];
        b_ih[l] = (const float*)d_in[3 + 4 * l];
        b_hh[l] = (const float*)d_in[4 + 4 * l];
    }
    const float* fc_w = (const float*)d_in[17];
    const float* fc_b = (const float*)d_in[18];
    float* out = (float*)d_out;

    char* wsb = (char*)d_ws;
    float* io  = (float*)wsb;                                   // 67,108,864 B
    float* xg  = (float*)(wsb + 67108864);                      // 33,554,432 B
    float* hst = (float*)(wsb + 67108864 + 33554432);           // 131,072 B
    float* cst = hst + BATCH * HID;                             // 131,072 B

    dim3 ggrid(8, 256);  // x = col tile (fast), y = row tile
    for (int l = 0; l < 4; ++l) {
        for (int cchunk = 0; cchunk < TSTEPS / TC; ++cchunk) {
            int t0 = cchunk * TC;
            if (l == 0)
                gemm_xg<100, true><<<ggrid, 256, 0, stream>>>(x, w_ih[0], b_ih[0], b_hh[0], xg, t0);
            else
                gemm_xg<128, false><<<ggrid, 256, 0, stream>>>(io, w_ih[l], b_ih[l], b_hh[l], xg, t0);
            lstm_rec<<<256, 512, 0, stream>>>(xg, w_hh[l], io, hst, cst, t0, cchunk == 0 ? 1 : 0);
        }
    }
    fc_kernel<<<1, 512, 0, stream>>>(hst, fc_w, fc_b, out);
}

// Round 5
// 2963.373 us; speedup vs baseline: 1.3681x; 1.0365x over previous
//
#include <hip/hip_runtime.h>

// LSTM: 4 layers, T=512, B=256, INPUT=100, H=128, gates=512 (i,f,g,o)
// Round 4: fp32 throughout.
//  - lstm_rec: quad structure (512 thr, thread (q,p) owns all 4 gates of unit
//    q over k-slice [32p,32p+32)). NEW: weights passed through
//    asm volatile("" : "+v") after load -> opaque register values, compiler
//    CANNOT rematerialize the loads inside the step loop. Rounds 1/3 showed
//    VGPR_Count=84/88 with 128 declared weights: backend re-loaded Whh from
//    L2 every step (~256KB/block/step ~= 0.8us/step, the bottleneck).
//    Verification: VGPR_Count >= ~168, dur ~25us. If WRITE_SIZE balloons,
//    the pin spilled to scratch instead -> abort this path.
//  - quad butterfly via mov_dpp (VALU) instead of __shfl_xor (ds_bpermute).
//  - gemm_xg / fc unchanged.
// ws: io [512*256*128]f32 @0 (67MB) | xg [64*256*512]f32 @67MB (33.5MB)
//     | hstate,cstate @100.6MB  => ~101MB total (known-safe size).

#define TSTEPS 512
#define BATCH  256
#define HID    128
#define GATES  512
#define TC     64

typedef float f32x4 __attribute__((ext_vector_type(4)));

__device__ __forceinline__ float sigmoid_f(float x) {
    return 1.0f / (1.0f + __expf(-x));
}
__device__ __forceinline__ float tanh_f(float x) {
    float e = __expf(2.0f * x);
    return 1.0f - 2.0f / (e + 1.0f);
}

// quad butterfly sum via DPP: xor1 = quad_perm[1,0,3,2] (0xB1),
// xor2 = quad_perm[2,3,0,1] (0x4E). Pure VALU, no LDS pipe.
__device__ __forceinline__ float quad_sum(float v) {
    int b = __builtin_amdgcn_mov_dpp(__float_as_int(v), 0xB1, 0xF, 0xF, true);
    float s = v + __int_as_float(b);
    int c = __builtin_amdgcn_mov_dpp(__float_as_int(s), 0x4E, 0xF, 0xF, true);
    return s + __int_as_float(c);
}

// ---------------- input-projection GEMM ----------------
// XG[r, j] = A[row r, :]·W[j, :] + b_ih[j] + b_hh[j]
// rows r = q*256 + b (t = t0+q), cols j in [0,512). 64x64 tile, 256 thr, 4x4.
template<int K, bool L0>
__global__ __launch_bounds__(256, 4)
void gemm_xg(const float* __restrict__ A, const float* __restrict__ W,
             const float* __restrict__ bih, const float* __restrict__ bhh,
             float* __restrict__ XG, int t0)
{
    __shared__ float As[32][68];  // As[kk][row]
    __shared__ float Bs[32][68];  // Bs[kk][col]
    const int tid  = threadIdx.x;
    const int flat = blockIdx.y * 8 + blockIdx.x;   // [0,2048)
    const int rt   = flat & 255;   // row tile
    const int ct   = flat >> 8;    // col tile 0..7
    const int j0   = ct * 64;
    const int R0   = rt * 64;
    const int ty = tid >> 4, tx = tid & 15;

    float acc[4][4] = {};

    for (int kt = 0; kt < K; kt += 32) {
        #pragma unroll
        for (int i = 0; i < 8; ++i) {
            int f  = tid + 256 * i;
            int r  = f >> 5, kk = f & 31;
            int k  = kt + kk;
            int Rg = R0 + r;
            int q  = Rg >> 8, b = Rg & 255;
            float av = 0.f, wv = 0.f;
            if (K == 128 || k < K) {
                av = L0 ? A[(b * TSTEPS + (t0 + q)) * K + k]
                        : A[((t0 + q) * BATCH + b) * K + k];
                wv = W[(j0 + r) * K + k];
            }
            As[kk][r] = av;
            Bs[kk][r] = wv;
        }
        __syncthreads();
        #pragma unroll 8
        for (int kk = 0; kk < 32; ++kk) {
            float4 a4 = *(const float4*)&As[kk][ty * 4];
            float4 b4 = *(const float4*)&Bs[kk][tx * 4];
            float aa[4] = {a4.x, a4.y, a4.z, a4.w};
            float bb[4] = {b4.x, b4.y, b4.z, b4.w};
            #pragma unroll
            for (int ii = 0; ii < 4; ++ii)
                #pragma unroll
                for (int jj = 0; jj < 4; ++jj)
                    acc[ii][jj] = fmaf(aa[ii], bb[jj], acc[ii][jj]);
        }
        __syncthreads();
    }

    float4 bi = *(const float4*)&bih[j0 + tx * 4];
    float4 bh = *(const float4*)&bhh[j0 + tx * 4];
    float bsum[4] = {bi.x + bh.x, bi.y + bh.y, bi.z + bh.z, bi.w + bh.w};
    #pragma unroll
    for (int ii = 0; ii < 4; ++ii) {
        int Rg = R0 + ty * 4 + ii;
        float4 st = {acc[ii][0] + bsum[0], acc[ii][1] + bsum[1],
                     acc[ii][2] + bsum[2], acc[ii][3] + bsum[3]};
        *(float4*)&XG[Rg * GATES + j0 + tx * 4] = st;
    }
}

// ---------------- recurrent scan ----------------
// One block (512 thr) per batch row. Thread (q = tid>>2, p = tid&3) owns all
// 4 gates of hidden unit q over k-slice [32p,32p+32). 128 weight VGPRs,
// pinned via asm. Quad DPP butterfly -> every lane gets complete i,f,g,o.
__global__ __attribute__((amdgpu_waves_per_eu(2, 2))) __launch_bounds__(512)
void lstm_rec(const float* __restrict__ XG, const float* __restrict__ Whh,
              float* __restrict__ Hout,
              float* __restrict__ hstate, float* __restrict__ cstate,
              int t0, int first)
{
    const int b   = blockIdx.x;
    const int tid = threadIdx.x;
    const int q   = tid >> 2;   // hidden unit 0..127
    const int p   = tid & 3;    // k-slice 0..3
    __shared__ float hbuf[2][144];  // unit u at u + 4*(u>>5); slice p at 36p

    // w4[g*8+j] = Whh[g*128+q][32p+4j .. +3] -> 128 VGPRs
    f32x4 w4[32];
    #pragma unroll
    for (int g = 0; g < 4; ++g) {
        const float* wp = Whh + (g * HID + q) * HID + p * 32;
        #pragma unroll
        for (int j = 0; j < 8; ++j)
            w4[g * 8 + j] = *(const f32x4*)(wp + 4 * j);
    }
    // PIN: opaque register values -> no rematerialization possible.
    #pragma unroll
    for (int i = 0; i < 32; ++i)
        asm volatile("" : "+v"(w4[i]));

    float c;
    if (first) {
        c = 0.f;
        if (p == 0) hbuf[0][q + 4 * (q >> 5)] = 0.f;
    } else {
        c = cstate[b * HID + q];
        if (p == 0) hbuf[0][q + 4 * (q >> 5)] = hstate[b * HID + q];
    }
    __syncthreads();

    // lane p streams gate p's xg for unit q
    const float* xgp = XG + b * GATES + p * HID + q;
    float xg_val = xgp[0];
    float h = 0.f;
    int cur = 0;
    const int hbase = 36 * p;   // 16 distinct banks per j-step + broadcast
    for (int s = 0; s < TC; ++s) {
        float xg_next = 0.f;
        if (s + 1 < TC) xg_next = xgp[(s + 1) * (BATCH * GATES)];

        float g0 = (p == 0) ? xg_val : 0.f;
        float g1 = (p == 1) ? xg_val : 0.f;
        float g2 = (p == 2) ? xg_val : 0.f;
        float g3 = (p == 3) ? xg_val : 0.f;
        #pragma unroll
        for (int j = 0; j < 8; ++j) {
            f32x4 hv = *(const f32x4*)&hbuf[cur][hbase + 4 * j];
            f32x4 w0 = w4[0 * 8 + j], w1 = w4[1 * 8 + j];
            f32x4 w2 = w4[2 * 8 + j], w3 = w4[3 * 8 + j];
            g0 = fmaf(w0.x, hv.x, g0); g1 = fmaf(w1.x, hv.x, g1);
            g2 = fmaf(w2.x, hv.x, g2); g3 = fmaf(w3.x, hv.x, g3);
            g0 = fmaf(w0.y, hv.y, g0); g1 = fmaf(w1.y, hv.y, g1);
            g2 = fmaf(w2.y, hv.y, g2); g3 = fmaf(w3.y, hv.y, g3);
            g0 = fmaf(w0.z, hv.z, g0); g1 = fmaf(w1.z, hv.z, g1);
            g2 = fmaf(w2.z, hv.z, g2); g3 = fmaf(w3.z, hv.z, g3);
            g0 = fmaf(w0.w, hv.w, g0); g1 = fmaf(w1.w, hv.w, g1);
            g2 = fmaf(w2.w, hv.w, g2); g3 = fmaf(w3.w, hv.w, g3);
        }
        // quad butterfly (DPP, VALU-only): all 4 p-lanes get full i,f,g,o
        g0 = quad_sum(g0);
        g1 = quad_sum(g1);
        g2 = quad_sum(g2);
        g3 = quad_sum(g3);

        c = sigmoid_f(g1) * c + sigmoid_f(g0) * tanh_f(g2);
        h = sigmoid_f(g3) * tanh_f(c);

        if (p == 0) {
            hbuf[cur ^ 1][q + 4 * (q >> 5)] = h;
            Hout[((t0 + s) * BATCH + b) * HID + q] = h;
        }
        __syncthreads();
        cur ^= 1;
        xg_val = xg_next;
    }
    if (p == 0) {
        hstate[b * HID + q] = h;
        cstate[b * HID + q] = c;
    }
}

// ---------------- final FC ----------------
__global__ __launch_bounds__(512)
void fc_kernel(const float* __restrict__ hstate, const float* __restrict__ fcw,
               const float* __restrict__ fcb, float* __restrict__ out)
{
    int idx = threadIdx.x;      // 512 = 256 rows x 2 outs
    int b = idx >> 1, o = idx & 1;
    float acc = fcb[o];
    #pragma unroll
    for (int k = 0; k < HID; ++k)
        acc = fmaf(hstate[b * HID + k], fcw[o * HID + k], acc);
    out[b * 2 + o] = acc;
}

extern "C" void kernel_launch(void* const* d_in, const int* in_sizes, int n_in,
                              void* d_out, int out_size, void* d_ws, size_t ws_size,
                              hipStream_t stream)
{
    const float* x = (const float*)d_in[0];
    const float* w_ih[4]; const float* w_hh[4];
    const float* b_ih[4]; const float* b_hh[4];
    for (int l = 0; l < 4; ++l) {
        w_ih[l] = (const float*)d_in[1 + 4 * l];
        w_hh[l] = (const float*)d_in[2 + 4 * l];
        b_ih[l] = (const float*)d_in[3 + 4 * l];
        b_hh[l] = (const float*)d_in[4 + 4 * l];
    }
    const float* fc_w = (const float*)d_in[17];
    const float* fc_b = (const float*)d_in[18];
    float* out = (float*)d_out;

    char* wsb = (char*)d_ws;
    float* io  = (float*)wsb;                                   // 67,108,864 B
    float* xg  = (float*)(wsb + 67108864);                      // 33,554,432 B
    float* hst = (float*)(wsb + 67108864 + 33554432);           // 131,072 B
    float* cst = hst + BATCH * HID;                             // 131,072 B

    dim3 ggrid(8, 256);  // x = col tile (fast), y = row tile
    for (int l = 0; l < 4; ++l) {
        for (int cchunk = 0; cchunk < TSTEPS / TC; ++cchunk) {
            int t0 = cchunk * TC;
            if (l == 0)
                gemm_xg<100, true><<<ggrid, 256, 0, stream>>>(x, w_ih[0], b_ih[0], b_hh[0], xg, t0);
            else
                gemm_xg<128, false><<<ggrid, 256, 0, stream>>>(io, w_ih[l], b_ih[l], b_hh[l], xg, t0);
            lstm_rec<<<256, 512, 0, stream>>>(xg, w_hh[l], io, hst, cst, t0, cchunk == 0 ? 1 : 0);
        }
    }
    fc_kernel<<<1, 512, 0, stream>>>(hst, fc_w, fc_b, out);
}